// Round 6
// baseline (454.620 us; speedup 1.0000x reference)
//
#include <hip/hip_runtime.h>
#include <hip/hip_bf16.h>
#include <stdint.h>

// ProjectiveAttention: out = softmax(h @ W @ h^T) @ h
// B=8, S=2048, D=800, all fp32 in/out.
// R4: deep-pipelined 256x256xBK64 8-wave GEMM template, split3-as-K-extended.
// R5: per-phase single staging bursts, counted fences.
// R6: remove ALL sched_barrier(0) pins (m141: pinning = -42%); explicit SW
// pipeline: each phase = {stage; [VMF]; BAR; MFMA_p; ds_reads for p+1; BAR}.
// Loads issue while MFMA pipe drains (no dep); fences repositioned one phase
// early (VMF(2)@ph0/ph2, VMF(3) both phases for BM=128) so every load's
// legal hoist ceiling equals its data guarantee. Hazard-audited: stage code
// motion bounded by memory-clobber VMFs, disjoint {lsA/lsB, dbuf, k-half}.

#define BB 8
#define SS 2048
#define DD 800
#define KP 832            // K padded to 13*64
#define M1 (BB*SS)        // 16384

typedef unsigned short u16;
typedef __attribute__((ext_vector_type(8))) short bf16x8;
typedef __attribute__((ext_vector_type(4))) float f32x4;

#define MFMA16(A, B, C) __builtin_amdgcn_mfma_f32_16x16x32_bf16(A, B, C, 0, 0, 0)
#define VMF(N) asm volatile("s_waitcnt vmcnt(" #N ")" ::: "memory")
#define BAR() __builtin_amdgcn_s_barrier()

__device__ __forceinline__ u16 f2bf(float x) {
    uint32_t u = __float_as_uint(x);
    uint32_t r = (u + 0x7fffu + ((u >> 16) & 1u)) >> 16;  // RTN-even
    return (u16)r;
}
__device__ __forceinline__ float bf2f(u16 h) {
    return __uint_as_float(((uint32_t)h) << 16);
}
__device__ __forceinline__ void gload16(const void* g, void* l) {
    __builtin_amdgcn_global_load_lds((__attribute__((address_space(1))) void*)g,
                                     (__attribute__((address_space(3))) void*)l,
                                     16, 0, 0);
}

// ---------------- prep kernels ----------------

// h (fp32 [16384][800]) -> h_hi/h_lo (bf16 [16384][832], k-pad zeroed)
__global__ __launch_bounds__(256) void hsplit_kernel(const float* __restrict__ x,
                                                     u16* __restrict__ hi,
                                                     u16* __restrict__ lo) {
    int idx = blockIdx.x * 256 + threadIdx.x;   // 16384*208 groups of 4 cols
    int rw = idx / 208, g = idx - rw * 208;
    ushort4 hv = {0, 0, 0, 0}, lv = {0, 0, 0, 0};
    if (g < 200) {
        float4 v = *(const float4*)(x + (long)rw * DD + g * 4);
        u16 h0 = f2bf(v.x), h1 = f2bf(v.y), h2 = f2bf(v.z), h3 = f2bf(v.w);
        hv = (ushort4){h0, h1, h2, h3};
        lv = (ushort4){f2bf(v.x - bf2f(h0)), f2bf(v.y - bf2f(h1)),
                       f2bf(v.z - bf2f(h2)), f2bf(v.w - bf2f(h3))};
    }
    *(ushort4*)(hi + (long)rw * KP + g * 4) = hv;
    *(ushort4*)(lo + (long)rw * KP + g * 4) = lv;
}

// W (fp32 [800][800]) -> Wt_hi/Wt_lo (bf16 [1024][832], transposed, pads zeroed)
__global__ __launch_bounds__(256) void wsplit_kernel(const float* __restrict__ W,
                                                     u16* __restrict__ hi,
                                                     u16* __restrict__ lo) {
    int idx = blockIdx.x * 256 + threadIdx.x;   // 1024*832
    int e = idx / KP, d = idx - e * KP;
    float v = (e < DD && d < DD) ? W[(long)d * DD + e] : 0.f;
    u16 h = f2bf(v);
    hi[idx] = h;
    lo[idx] = f2bf(v - bf2f(h));
}

// h_hi (bf16 [8][2048][832]) -> hT (bf16 [8][1024][2048], pad rows zeroed)
__global__ void transpose_kernel(const u16* __restrict__ h_hi, u16* __restrict__ hT) {
    __shared__ u16 tile[32][33];
    int b = blockIdx.z;
    int t0 = blockIdx.x * 32, d0 = blockIdx.y * 32;
    int lx = threadIdx.x, ly = threadIdx.y;
    for (int i = ly; i < 32; i += 8) {
        int d = d0 + lx;
        tile[i][lx] = (d < DD) ? h_hi[((long)b * SS + t0 + i) * KP + d] : (u16)0;
    }
    __syncthreads();
    for (int i = ly; i < 32; i += 8) {
        hT[((long)b * 1024 + d0 + i) * SS + t0 + lx] = tile[lx][i];
    }
}

// ---------------- softmax (one block per row, in-place fp32 -> bf16 attn) ------

__global__ __launch_bounds__(256) void softmax_kernel(float* __restrict__ scores) {
    const long row = blockIdx.x;
    float* p = scores + row * (long)SS;
    const int tid = threadIdx.x;
    const int lane = tid & 63, wid = tid >> 6;
    __shared__ float red[8];

    float v[8];
    float mx = -3.4e38f;
#pragma unroll
    for (int j = 0; j < 8; ++j) { v[j] = p[tid + 256 * j]; mx = fmaxf(mx, v[j]); }
#pragma unroll
    for (int o = 32; o; o >>= 1) mx = fmaxf(mx, __shfl_xor(mx, o, 64));
    if (lane == 0) red[wid] = mx;
    __syncthreads();
    mx = fmaxf(fmaxf(red[0], red[1]), fmaxf(red[2], red[3]));

    float sum = 0.f;
#pragma unroll
    for (int j = 0; j < 8; ++j) { v[j] = __expf(v[j] - mx); sum += v[j]; }
#pragma unroll
    for (int o = 32; o; o >>= 1) sum += __shfl_xor(sum, o, 64);
    if (lane == 0) red[4 + wid] = sum;
    __syncthreads();
    const float inv = 1.f / (red[4] + red[5] + red[6] + red[7]);

    u16* attn = (u16*)p;
#pragma unroll
    for (int j = 0; j < 8; ++j) attn[tid + 256 * j] = f2bf(v[j] * inv);
}

// ---------------- deep-pipelined GEMM: C[m][n] = sum_k A[m][k]*B[n][k] ----------
// BM x 256 tile, BK=64 (2 ksubs of 32), 512 threads (8 waves). M batch-merged;
// when sB!=0, batch = m0>>11. SPLIT3: K'=3K via per-K-tile variant
// (Ahi,Bhi)/(Ahi,Blo)/(Alo,Bhi). LDS: per operand [2 dbuf][2 ksub][cells][512u16],
// fragment read = cell + lane*16B (conflict-free, 0 conflicts R2-verified);
// gload dest linear, source permuted (rule #21).
//
// Per-K-tile schedule (BM=256), SW-pipelined register loads:
//   ph0: stA(t+1.s0); VMF(2|0); BAR; M0(a,b01@s0); G1(b23@s0);   BAR
//   ph1: stB(t+1.s0);           BAR; M1(a,b23@s0); G2(a,b01@s1); BAR
//   ph2: stA(t+1.s1); VMF(2|0); BAR; M2(a,b01@s1); G3(b23@s1);   BAR
//   ph3: stB(t+1.s1);           BAR; M3(a,b23@s1); G0'(next s0); BAR
// VMF(2)@ph0 drains everything except the just-issued pair => t.s1 landed;
// VMF(2)@ph2 => (t+1).s0 landed (G0's guarantee). Loads after MFMA clusters
// issue while the matrix pipe drains (no dep) — LDS/MFMA pipes overlap.

template <int BM, int SPLIT3, int SPLIT_OUT, int NGUARD>
__global__ __launch_bounds__(512, 2) void gemm8(
    const u16* __restrict__ Ahi, const u16* __restrict__ Alo, int lda,
    const u16* __restrict__ Bhi, const u16* __restrict__ Blo, long sB, int ldb,
    float* __restrict__ C, u16* __restrict__ Chi, u16* __restrict__ Clo,
    int ldc, int Nlim, int Nbuf, int ksteps, int gmt) {
    constexpr int ABUF = BM * 64;          // u16 per A dbuf
    constexpr int AS = (BM / 16) * 512;    // u16 per A ksub region
    constexpr int MFR = (BM == 256) ? 8 : 4;
    extern __shared__ u16 smem[];
    u16* lsA = smem;                       // [2][ABUF]
    u16* lsB = smem + 2 * ABUF;            // [2][16384]

    const int tid = threadIdx.x;
    const int lane = tid & 63, wid = tid >> 6;
    const int wm = wid >> 2, wn = wid & 3;

    // bijective XCD remap (m204) on linearized grid, mt-fastest
    const int nwg = gridDim.x;
    const int orig = blockIdx.x;
    const int q = nwg >> 3, r = nwg & 7;
    const int xcd = orig & 7;
    const int wg = (xcd < r ? xcd * (q + 1) : r * (q + 1) + (xcd - r) * q) + (orig >> 3);
    const int m0 = (wg % gmt) * BM;
    const int n0 = (wg / gmt) * 256;

    const long boff = sB ? (long)(m0 >> 11) * sB : 0;
    const u16* Bh = Bhi + boff;
    const u16* Bl = SPLIT3 ? (Blo + boff) : nullptr;

    const int rlane = lane & 15;
    const int l8 = lane * 8;
    const int kl = (lane >> 4) * 8;        // k sub-offset within staging source

    f32x4 acc[MFR][4];
#pragma unroll
    for (int i = 0; i < MFR; ++i)
#pragma unroll
        for (int j = 0; j < 4; ++j) acc[i][j] = (f32x4){0.f, 0.f, 0.f, 0.f};

    auto resolve = [&](int t, const u16*& As, const u16*& Bs, int& kb) {
        if (SPLIT3) {
            int kk = t / 3, v = t - kk * 3;
            As = (v == 2) ? Alo : Ahi;
            Bs = (v == 1) ? Bl : Bh;
            kb = kk * 64;
        } else {
            As = Ahi; Bs = Bh; kb = t * 64;
        }
    };

    auto stageA = [&](const u16* As, int kb, int s, int d) {
        const int kg = kb + s * 32 + kl;
        u16* aB = lsA + d * ABUF + s * AS;
        if (BM == 256) {
            const int f = 2 * wid;
            gload16(As + (long)(m0 + f * 16 + rlane) * lda + kg, aB + f * 512);
            gload16(As + (long)(m0 + f * 16 + 16 + rlane) * lda + kg, aB + (f + 1) * 512);
        } else {
            gload16(As + (long)(m0 + wid * 16 + rlane) * lda + kg, aB + wid * 512);
        }
    };
    auto stageB = [&](const u16* Bs, int kb, int s, int d) {
        const int kg = kb + s * 32 + kl;
        u16* bB = lsB + d * 16384 + s * 8192;
        const int f = 2 * wid;
        gload16(Bs + (long)(n0 + f * 16 + rlane) * ldb + kg, bB + f * 512);
        gload16(Bs + (long)(n0 + f * 16 + 16 + rlane) * ldb + kg, bB + (f + 1) * 512);
    };

    if constexpr (BM == 256) {
        bf16x8 a[8], b0, b1;
        // prologue: stage tile 0 fully; wait s0; load G0 (a@s0 + b01@s0)
        {
            const u16 *As, *Bs; int kb;
            resolve(0, As, Bs, kb);
            stageA(As, kb, 0, 0);
            stageB(Bs, kb, 0, 0);
            stageA(As, kb, 1, 0);
            stageB(Bs, kb, 1, 0);
            VMF(4);
            BAR();
            const u16* ap = lsA + wm * 4096 + l8;
#pragma unroll
            for (int i = 0; i < 8; ++i) a[i] = *(const bf16x8*)(ap + i * 512);
            const u16* bp = lsB + wn * 2048 + l8;
            b0 = *(const bf16x8*)bp;
            b1 = *(const bf16x8*)(bp + 512);
        }
        for (int t = 0; t < ksteps; ++t) {
            const int d = t & 1;
            const bool h1 = (t + 1 < ksteps);
            const u16* aBuf = lsA + d * ABUF;
            const u16* bBuf = lsB + d * 16384;
            const u16 *As1, *Bs1; int kb1;
            resolve(h1 ? t + 1 : t, As1, Bs1, kb1);
            // ph0: stage (t+1).A.s0; fence drains t.s1; M0; load G1(b23@s0)
            if (h1) { stageA(As1, kb1, 0, d ^ 1); VMF(2); } else { VMF(0); }
            BAR();
            __builtin_amdgcn_s_setprio(1);
#pragma unroll
            for (int i = 0; i < 8; ++i) {
                acc[i][0] = MFMA16(a[i], b0, acc[i][0]);
                acc[i][1] = MFMA16(a[i], b1, acc[i][1]);
            }
            __builtin_amdgcn_s_setprio(0);
            {
                const u16* bp = bBuf + wn * 2048 + 1024 + l8;
                b0 = *(const bf16x8*)bp;
                b1 = *(const bf16x8*)(bp + 512);
            }
            BAR();
            // ph1: stage (t+1).B.s0; M1; load G2(a@s1 + b01@s1)
            if (h1) stageB(Bs1, kb1, 0, d ^ 1);
            BAR();
            __builtin_amdgcn_s_setprio(1);
#pragma unroll
            for (int i = 0; i < 8; ++i) {
                acc[i][2] = MFMA16(a[i], b0, acc[i][2]);
                acc[i][3] = MFMA16(a[i], b1, acc[i][3]);
            }
            __builtin_amdgcn_s_setprio(0);
            {
                const u16* ap = aBuf + AS + wm * 4096 + l8;
#pragma unroll
                for (int i = 0; i < 8; ++i) a[i] = *(const bf16x8*)(ap + i * 512);
                const u16* bp = bBuf + 8192 + wn * 2048 + l8;
                b0 = *(const bf16x8*)bp;
                b1 = *(const bf16x8*)(bp + 512);
            }
            BAR();
            // ph2: stage (t+1).A.s1; fence drains (t+1).s0; M2; load G3(b23@s1)
            if (h1) { stageA(As1, kb1, 1, d ^ 1); VMF(2); } else { VMF(0); }
            BAR();
            __builtin_amdgcn_s_setprio(1);
#pragma unroll
            for (int i = 0; i < 8; ++i) {
                acc[i][0] = MFMA16(a[i], b0, acc[i][0]);
                acc[i][1] = MFMA16(a[i], b1, acc[i][1]);
            }
            __builtin_amdgcn_s_setprio(0);
            {
                const u16* bp = bBuf + 8192 + wn * 2048 + 1024 + l8;
                b0 = *(const bf16x8*)bp;
                b1 = *(const bf16x8*)(bp + 512);
            }
            BAR();
            // ph3: stage (t+1).B.s1; M3; load G0'(next tile a@s0 + b01@s0)
            if (h1) stageB(Bs1, kb1, 1, d ^ 1);
            BAR();
            __builtin_amdgcn_s_setprio(1);
#pragma unroll
            for (int i = 0; i < 8; ++i) {
                acc[i][2] = MFMA16(a[i], b0, acc[i][2]);
                acc[i][3] = MFMA16(a[i], b1, acc[i][3]);
            }
            __builtin_amdgcn_s_setprio(0);
            if (h1) {
                const u16* aBn = lsA + (d ^ 1) * ABUF;
                const u16* bBn = lsB + (d ^ 1) * 16384;
                const u16* ap = aBn + wm * 4096 + l8;
#pragma unroll
                for (int i = 0; i < 8; ++i) a[i] = *(const bf16x8*)(ap + i * 512);
                const u16* bp = bBn + wn * 2048 + l8;
                b0 = *(const bf16x8*)bp;
                b1 = *(const bf16x8*)(bp + 512);
            }
            BAR();
        }
    } else {
        bf16x8 a[4], b[4];
        // prologue: stage tile 0; wait s0; load G0 (a@s0 + b@s0)
        {
            const u16 *As, *Bs; int kb;
            resolve(0, As, Bs, kb);
            stageA(As, kb, 0, 0);
            stageB(Bs, kb, 0, 0);
            stageA(As, kb, 1, 0);
            stageB(Bs, kb, 1, 0);
            VMF(3);
            BAR();
            const u16* ap = lsA + wm * 2048 + l8;
#pragma unroll
            for (int i = 0; i < 4; ++i) a[i] = *(const bf16x8*)(ap + i * 512);
            const u16* bp = lsB + wn * 2048 + l8;
#pragma unroll
            for (int j = 0; j < 4; ++j) b[j] = *(const bf16x8*)(bp + j * 512);
        }
        for (int t = 0; t < ksteps; ++t) {
            const int d = t & 1;
            const bool h1 = (t + 1 < ksteps);
            const u16* aBuf = lsA + d * ABUF;
            const u16* bBuf = lsB + d * 16384;
            const u16 *As1, *Bs1; int kb1;
            resolve(h1 ? t + 1 : t, As1, Bs1, kb1);
            // ph0: stage (t+1).s0; fence drains t.s1; M0; load G1(s1)
            if (h1) { stageA(As1, kb1, 0, d ^ 1); stageB(Bs1, kb1, 0, d ^ 1); VMF(3); }
            else { VMF(0); }
            BAR();
            __builtin_amdgcn_s_setprio(1);
#pragma unroll
            for (int i = 0; i < 4; ++i)
#pragma unroll
                for (int j = 0; j < 4; ++j) acc[i][j] = MFMA16(a[i], b[j], acc[i][j]);
            __builtin_amdgcn_s_setprio(0);
            {
                const u16* ap = aBuf + AS + wm * 2048 + l8;
#pragma unroll
                for (int i = 0; i < 4; ++i) a[i] = *(const bf16x8*)(ap + i * 512);
                const u16* bp = bBuf + 8192 + wn * 2048 + l8;
#pragma unroll
                for (int j = 0; j < 4; ++j) b[j] = *(const bf16x8*)(bp + j * 512);
            }
            BAR();
            // ph1: stage (t+1).s1; fence drains (t+1).s0; M1; load G0'(next s0)
            if (h1) { stageA(As1, kb1, 1, d ^ 1); stageB(Bs1, kb1, 1, d ^ 1); VMF(3); }
            else { VMF(0); }
            BAR();
            __builtin_amdgcn_s_setprio(1);
#pragma unroll
            for (int i = 0; i < 4; ++i)
#pragma unroll
                for (int j = 0; j < 4; ++j) acc[i][j] = MFMA16(a[i], b[j], acc[i][j]);
            __builtin_amdgcn_s_setprio(0);
            if (h1) {
                const u16* aBn = lsA + (d ^ 1) * ABUF;
                const u16* bBn = lsB + (d ^ 1) * 16384;
                const u16* ap = aBn + wm * 2048 + l8;
#pragma unroll
                for (int i = 0; i < 4; ++i) a[i] = *(const bf16x8*)(ap + i * 512);
                const u16* bp = bBn + wn * 2048 + l8;
#pragma unroll
                for (int j = 0; j < 4; ++j) b[j] = *(const bf16x8*)(bp + j * 512);
            }
            BAR();
        }
    }

    // epilogue: C/D layout col=lane&15, row=(lane>>4)*4+reg (R1-verified)
    const int crow = m0 + wm * (BM / 2) + (lane >> 4) * 4;
    const int ccol = n0 + wn * 64 + rlane;
#pragma unroll
    for (int i = 0; i < MFR; ++i) {
#pragma unroll
        for (int j = 0; j < 4; ++j) {
            const int nn = ccol + j * 16;
            if (NGUARD && nn >= Nbuf) continue;
#pragma unroll
            for (int rr = 0; rr < 4; ++rr) {
                const int mm = crow + i * 16 + rr;
                const long off = (long)mm * ldc + nn;
                float v = acc[i][j][rr];
                if (NGUARD && nn >= Nlim) v = 0.f;
                if (SPLIT_OUT) {
                    u16 hh = f2bf(v);
                    Chi[off] = hh;
                    Clo[off] = f2bf(v - bf2f(hh));
                } else {
                    C[off] = v;
                }
            }
        }
    }
}

// ---------------- host ----------------

extern "C" void kernel_launch(void* const* d_in, const int* in_sizes, int n_in,
                              void* d_out, int out_size, void* d_ws, size_t ws_size,
                              hipStream_t stream) {
    const float* h = (const float*)d_in[0];
    const float* W = (const float*)d_in[1];
    float* out = (float*)d_out;

    char* ws = (char*)d_ws;
    size_t off = 0;
    auto alloc = [&](size_t bytes) -> void* {
        void* p = ws + off;
        off += (bytes + 255) & ~(size_t)255;
        return p;
    };
    const size_t MD = (size_t)M1 * KP;
    u16* h_hi  = (u16*)alloc(MD * 2);
    u16* h_lo  = (u16*)alloc(MD * 2);
    u16* hW_hi = (u16*)alloc(MD * 2);
    u16* hW_lo = (u16*)alloc(MD * 2);
    u16* hT    = (u16*)alloc((size_t)BB * 1024 * SS * 2);
    u16* Wt_hi = (u16*)alloc((size_t)1024 * KP * 2);
    u16* Wt_lo = (u16*)alloc((size_t)1024 * KP * 2);
    float* scores = (float*)alloc((size_t)4 * SS * SS * 4);   // 4-batch chunk

    hipFuncSetAttribute(reinterpret_cast<const void*>(&gemm8<256, 1, 1, 1>),
                        hipFuncAttributeMaxDynamicSharedMemorySize, 131072);
    hipFuncSetAttribute(reinterpret_cast<const void*>(&gemm8<256, 1, 0, 0>),
                        hipFuncAttributeMaxDynamicSharedMemorySize, 131072);
    hipFuncSetAttribute(reinterpret_cast<const void*>(&gemm8<128, 0, 0, 1>),
                        hipFuncAttributeMaxDynamicSharedMemorySize, 98304);

    // prep
    hsplit_kernel<<<dim3(16384 * 208 / 256), dim3(256), 0, stream>>>(h, h_hi, h_lo);
    wsplit_kernel<<<dim3(1024 * KP / 256), dim3(256), 0, stream>>>(W, Wt_hi, Wt_lo);
    transpose_kernel<<<dim3(SS / 32, 32, BB), dim3(32, 8), 0, stream>>>(h_hi, hT);

    // GEMM1: hW = h @ W  (M=16384, N=1024pad, K'=39 tiles) split-out, zero k-pad
    gemm8<256, 1, 1, 1><<<dim3(256), dim3(512), 131072, stream>>>(
        h_hi, h_lo, KP,
        Wt_hi, Wt_lo, 0L, KP,
        nullptr, hW_hi, hW_lo,
        KP, DD, KP, 39, 64);

    for (int b0 = 0; b0 < BB; b0 += 4) {
        const long aoff = (long)b0 * SS * KP;
        // GEMM2: scores = hW @ h^T  (chunk M=8192 m-merged, N=2048/batch, K'=39)
        gemm8<256, 1, 0, 0><<<dim3(256), dim3(512), 131072, stream>>>(
            hW_hi + aoff, hW_lo + aoff, KP,
            h_hi + aoff, h_lo + aoff, (long)SS * KP, KP,
            scores, nullptr, nullptr,
            SS, SS, SS, 39, 32);
        // softmax rows -> bf16 attn in place (pitch 4096 u16)
        softmax_kernel<<<dim3(4 * SS), dim3(256), 0, stream>>>(scores);
        // PV: out = attn @ h  (chunk M=8192, N=1024pad, K=2048, BM=128)
        gemm8<128, 0, 0, 1><<<dim3(256), dim3(512), 98304, stream>>>(
            (const u16*)scores, nullptr, SS * 2,
            hT + (long)b0 * 1024 * SS, nullptr, (long)1024 * SS, SS,
            out + (long)b0 * SS * DD, nullptr, nullptr,
            DD, DD, DD, 32, 64);
    }
}

// Round 7
// 437.550 us; speedup vs baseline: 1.0390x; 1.0390x over previous
//
#include <hip/hip_runtime.h>
#include <hip/hip_bf16.h>
#include <stdint.h>

// ProjectiveAttention: out = softmax(h @ W @ h^T) @ h
// B=8, S=2048, D=800, all fp32 in/out.
// R4: deep-pipelined 256x256xBK64 8-wave GEMM template, split3-as-K-extended.
// R7: m201-faithful phases. Phase = {ds_read THIS phase's fragments (top,
// pre-barrier -> latency hides under barrier sync); stage ONE burst of t+1;
// [counted fence]; BAR; setprio; 16 MFMA; setprio; BAR}. Fences re-derived
// for reads-at-top: a fence must precede (by >=1 phase + a barrier) the reads
// it protects. BM=256: fences at p1,p3 only, VMF(4) steady (2 bursts in
// flight); VMF(0) only in last-tile tail. BM=128: VMF(3) per phase.
// Fence induction (steady, bursts = 2 gload instr):
//   issue order: A(t).s0@p0(t-1), B(t).s0@p1(t-1), A(t).s1@p2(t-1), B(t).s1@p3(t-1)
//   F@p3(t-1) = VMF(4) -> drains A(t).s0,B(t).s0 (read at p0/p1(t))
//   F@p1(t)   = VMF(4) -> drains A(t).s1,B(t).s1 (read at p2/p3(t))
// Fixes R6's latent race (VMF(2)@ph2 left stB(t,s0) un-landed for G0').

#define BB 8
#define SS 2048
#define DD 800
#define KP 832            // K padded to 13*64
#define M1 (BB*SS)        // 16384

typedef unsigned short u16;
typedef __attribute__((ext_vector_type(8))) short bf16x8;
typedef __attribute__((ext_vector_type(4))) float f32x4;

#define MFMA16(A, B, C) __builtin_amdgcn_mfma_f32_16x16x32_bf16(A, B, C, 0, 0, 0)
#define VMF(N) asm volatile("s_waitcnt vmcnt(" #N ")" ::: "memory")
#define BAR() __builtin_amdgcn_s_barrier()

__device__ __forceinline__ u16 f2bf(float x) {
    uint32_t u = __float_as_uint(x);
    uint32_t r = (u + 0x7fffu + ((u >> 16) & 1u)) >> 16;  // RTN-even
    return (u16)r;
}
__device__ __forceinline__ float bf2f(u16 h) {
    return __uint_as_float(((uint32_t)h) << 16);
}
__device__ __forceinline__ void gload16(const void* g, void* l) {
    __builtin_amdgcn_global_load_lds((__attribute__((address_space(1))) void*)g,
                                     (__attribute__((address_space(3))) void*)l,
                                     16, 0, 0);
}

// ---------------- prep kernels ----------------

// h (fp32 [16384][800]) -> h_hi/h_lo (bf16 [16384][832], k-pad zeroed)
__global__ __launch_bounds__(256) void hsplit_kernel(const float* __restrict__ x,
                                                     u16* __restrict__ hi,
                                                     u16* __restrict__ lo) {
    int idx = blockIdx.x * 256 + threadIdx.x;   // 16384*208 groups of 4 cols
    int rw = idx / 208, g = idx - rw * 208;
    ushort4 hv = {0, 0, 0, 0}, lv = {0, 0, 0, 0};
    if (g < 200) {
        float4 v = *(const float4*)(x + (long)rw * DD + g * 4);
        u16 h0 = f2bf(v.x), h1 = f2bf(v.y), h2 = f2bf(v.z), h3 = f2bf(v.w);
        hv = (ushort4){h0, h1, h2, h3};
        lv = (ushort4){f2bf(v.x - bf2f(h0)), f2bf(v.y - bf2f(h1)),
                       f2bf(v.z - bf2f(h2)), f2bf(v.w - bf2f(h3))};
    }
    *(ushort4*)(hi + (long)rw * KP + g * 4) = hv;
    *(ushort4*)(lo + (long)rw * KP + g * 4) = lv;
}

// W (fp32 [800][800]) -> Wt_hi/Wt_lo (bf16 [1024][832], transposed, pads zeroed)
__global__ __launch_bounds__(256) void wsplit_kernel(const float* __restrict__ W,
                                                     u16* __restrict__ hi,
                                                     u16* __restrict__ lo) {
    int idx = blockIdx.x * 256 + threadIdx.x;   // 1024*832
    int e = idx / KP, d = idx - e * KP;
    float v = (e < DD && d < DD) ? W[(long)d * DD + e] : 0.f;
    u16 h = f2bf(v);
    hi[idx] = h;
    lo[idx] = f2bf(v - bf2f(h));
}

// h_hi (bf16 [8][2048][832]) -> hT (bf16 [8][1024][2048], pad rows zeroed)
__global__ void transpose_kernel(const u16* __restrict__ h_hi, u16* __restrict__ hT) {
    __shared__ u16 tile[32][33];
    int b = blockIdx.z;
    int t0 = blockIdx.x * 32, d0 = blockIdx.y * 32;
    int lx = threadIdx.x, ly = threadIdx.y;
    for (int i = ly; i < 32; i += 8) {
        int d = d0 + lx;
        tile[i][lx] = (d < DD) ? h_hi[((long)b * SS + t0 + i) * KP + d] : (u16)0;
    }
    __syncthreads();
    for (int i = ly; i < 32; i += 8) {
        hT[((long)b * 1024 + d0 + i) * SS + t0 + lx] = tile[lx][i];
    }
}

// ---------------- softmax (one block per row, in-place fp32 -> bf16 attn) ------

__global__ __launch_bounds__(256) void softmax_kernel(float* __restrict__ scores) {
    const long row = blockIdx.x;
    float* p = scores + row * (long)SS;
    const int tid = threadIdx.x;
    const int lane = tid & 63, wid = tid >> 6;
    __shared__ float red[8];

    float v[8];
    float mx = -3.4e38f;
#pragma unroll
    for (int j = 0; j < 8; ++j) { v[j] = p[tid + 256 * j]; mx = fmaxf(mx, v[j]); }
#pragma unroll
    for (int o = 32; o; o >>= 1) mx = fmaxf(mx, __shfl_xor(mx, o, 64));
    if (lane == 0) red[wid] = mx;
    __syncthreads();
    mx = fmaxf(fmaxf(red[0], red[1]), fmaxf(red[2], red[3]));

    float sum = 0.f;
#pragma unroll
    for (int j = 0; j < 8; ++j) { v[j] = __expf(v[j] - mx); sum += v[j]; }
#pragma unroll
    for (int o = 32; o; o >>= 1) sum += __shfl_xor(sum, o, 64);
    if (lane == 0) red[4 + wid] = sum;
    __syncthreads();
    const float inv = 1.f / (red[4] + red[5] + red[6] + red[7]);

    u16* attn = (u16*)p;
#pragma unroll
    for (int j = 0; j < 8; ++j) attn[tid + 256 * j] = f2bf(v[j] * inv);
}

// ---------------- deep-pipelined GEMM: C[m][n] = sum_k A[m][k]*B[n][k] ----------
// BM x 256 tile, BK=64 (2 ksubs of 32), 512 threads (8 waves, 2Mx4N).
// M batch-merged; when sB!=0, batch = m0>>11. SPLIT3: K'=3K via per-K-tile
// variant (Ahi,Bhi)/(Ahi,Blo)/(Alo,Bhi). LDS per operand:
// [2 dbuf][2 ksub][cells][512u16]; fragment read = cell + lane*16B
// (conflict-free, 0 conflicts verified); gload dest linear, src permuted.

template <int BM, int SPLIT3, int SPLIT_OUT, int NGUARD>
__global__ __launch_bounds__(512, 2) void gemm8(
    const u16* __restrict__ Ahi, const u16* __restrict__ Alo, int lda,
    const u16* __restrict__ Bhi, const u16* __restrict__ Blo, long sB, int ldb,
    float* __restrict__ C, u16* __restrict__ Chi, u16* __restrict__ Clo,
    int ldc, int Nlim, int Nbuf, int ksteps, int gmt) {
    constexpr int ABUF = BM * 64;          // u16 per A dbuf
    constexpr int AS = (BM / 16) * 512;    // u16 per A ksub region
    constexpr int MFR = (BM == 256) ? 8 : 4;
    extern __shared__ u16 smem[];
    u16* lsA = smem;                       // [2][ABUF]
    u16* lsB = smem + 2 * ABUF;            // [2][16384]

    const int tid = threadIdx.x;
    const int lane = tid & 63, wid = tid >> 6;
    const int wm = wid >> 2, wn = wid & 3;

    // bijective XCD remap (m204) on linearized grid, mt-fastest
    const int nwg = gridDim.x;
    const int orig = blockIdx.x;
    const int q = nwg >> 3, r = nwg & 7;
    const int xcd = orig & 7;
    const int wg = (xcd < r ? xcd * (q + 1) : r * (q + 1) + (xcd - r) * q) + (orig >> 3);
    const int m0 = (wg % gmt) * BM;
    const int n0 = (wg / gmt) * 256;

    const long boff = sB ? (long)(m0 >> 11) * sB : 0;
    const u16* Bh = Bhi + boff;
    const u16* Bl = SPLIT3 ? (Blo + boff) : nullptr;

    const int rlane = lane & 15;
    const int l8 = lane * 8;
    const int kl = (lane >> 4) * 8;        // k sub-offset within staging source

    f32x4 acc[MFR][4];
#pragma unroll
    for (int i = 0; i < MFR; ++i)
#pragma unroll
        for (int j = 0; j < 4; ++j) acc[i][j] = (f32x4){0.f, 0.f, 0.f, 0.f};

    auto resolve = [&](int t, const u16*& As, const u16*& Bs, int& kb) {
        if (SPLIT3) {
            int kk = t / 3, v = t - kk * 3;
            As = (v == 2) ? Alo : Ahi;
            Bs = (v == 1) ? Bl : Bh;
            kb = kk * 64;
        } else {
            As = Ahi; Bs = Bh; kb = t * 64;
        }
    };

    auto stageA = [&](const u16* As, int kb, int s, int d) {
        const int kg = kb + s * 32 + kl;
        u16* aB = lsA + d * ABUF + s * AS;
        if (BM == 256) {
            const int f = 2 * wid;
            gload16(As + (long)(m0 + f * 16 + rlane) * lda + kg, aB + f * 512);
            gload16(As + (long)(m0 + f * 16 + 16 + rlane) * lda + kg, aB + (f + 1) * 512);
        } else {
            gload16(As + (long)(m0 + wid * 16 + rlane) * lda + kg, aB + wid * 512);
        }
    };
    auto stageB = [&](const u16* Bs, int kb, int s, int d) {
        const int kg = kb + s * 32 + kl;
        u16* bB = lsB + d * 16384 + s * 8192;
        const int f = 2 * wid;
        gload16(Bs + (long)(n0 + f * 16 + rlane) * ldb + kg, bB + f * 512);
        gload16(Bs + (long)(n0 + f * 16 + 16 + rlane) * ldb + kg, bB + (f + 1) * 512);
    };

    if constexpr (BM == 256) {
        // prologue: stage tile 0 fully; drain s0 pair (VMF(4)); barrier
        {
            const u16 *As, *Bs; int kb;
            resolve(0, As, Bs, kb);
            stageA(As, kb, 0, 0);
            stageB(Bs, kb, 0, 0);
            stageA(As, kb, 1, 0);
            stageB(Bs, kb, 1, 0);
            VMF(4);
            BAR();
        }
        for (int t = 0; t < ksteps; ++t) {
            const int d = t & 1;
            const bool h1 = (t + 1 < ksteps);
            const u16* aBuf = lsA + d * ABUF;
            const u16* bBuf = lsB + d * 16384;
            const u16 *As1, *Bs1; int kb1;
            resolve(h1 ? t + 1 : t, As1, Bs1, kb1);
            bf16x8 a[8], b0, b1;
            // p0: reads a8@s0 + b01@s0 (fenced @p3(t-1)+BAR); stage A(t+1).s0
            {
                const u16* ap = aBuf + wm * 4096 + l8;
#pragma unroll
                for (int i = 0; i < 8; ++i) a[i] = *(const bf16x8*)(ap + i * 512);
                const u16* bp = bBuf + wn * 2048 + l8;
                b0 = *(const bf16x8*)bp;
                b1 = *(const bf16x8*)(bp + 512);
                if (h1) stageA(As1, kb1, 0, d ^ 1);
                BAR();
                __builtin_amdgcn_s_setprio(1);
#pragma unroll
                for (int i = 0; i < 8; ++i) {
                    acc[i][0] = MFMA16(a[i], b0, acc[i][0]);
                    acc[i][1] = MFMA16(a[i], b1, acc[i][1]);
                }
                __builtin_amdgcn_s_setprio(0);
                BAR();
            }
            // p1: reads b23@s0; stage B(t+1).s0; FENCE: drain A(t).s1,B(t).s1
            {
                const u16* bp = bBuf + wn * 2048 + 1024 + l8;
                b0 = *(const bf16x8*)bp;
                b1 = *(const bf16x8*)(bp + 512);
                if (h1) { stageB(Bs1, kb1, 0, d ^ 1); VMF(4); } else { VMF(0); }
                BAR();
                __builtin_amdgcn_s_setprio(1);
#pragma unroll
                for (int i = 0; i < 8; ++i) {
                    acc[i][2] = MFMA16(a[i], b0, acc[i][2]);
                    acc[i][3] = MFMA16(a[i], b1, acc[i][3]);
                }
                __builtin_amdgcn_s_setprio(0);
                BAR();
            }
            // p2: reads a8@s1 + b01@s1 (fenced @p1+BAR); stage A(t+1).s1
            {
                const u16* ap = aBuf + AS + wm * 4096 + l8;
#pragma unroll
                for (int i = 0; i < 8; ++i) a[i] = *(const bf16x8*)(ap + i * 512);
                const u16* bp = bBuf + 8192 + wn * 2048 + l8;
                b0 = *(const bf16x8*)bp;
                b1 = *(const bf16x8*)(bp + 512);
                if (h1) stageA(As1, kb1, 1, d ^ 1);
                BAR();
                __builtin_amdgcn_s_setprio(1);
#pragma unroll
                for (int i = 0; i < 8; ++i) {
                    acc[i][0] = MFMA16(a[i], b0, acc[i][0]);
                    acc[i][1] = MFMA16(a[i], b1, acc[i][1]);
                }
                __builtin_amdgcn_s_setprio(0);
                BAR();
            }
            // p3: reads b23@s1; stage B(t+1).s1; FENCE: drain A(t+1).s0,B(t+1).s0
            {
                const u16* bp = bBuf + 8192 + wn * 2048 + 1024 + l8;
                b0 = *(const bf16x8*)bp;
                b1 = *(const bf16x8*)(bp + 512);
                if (h1) { stageB(Bs1, kb1, 1, d ^ 1); VMF(4); }
                BAR();
                __builtin_amdgcn_s_setprio(1);
#pragma unroll
                for (int i = 0; i < 8; ++i) {
                    acc[i][2] = MFMA16(a[i], b0, acc[i][2]);
                    acc[i][3] = MFMA16(a[i], b1, acc[i][3]);
                }
                __builtin_amdgcn_s_setprio(0);
                BAR();
            }
        }
    } else {
        // prologue
        {
            const u16 *As, *Bs; int kb;
            resolve(0, As, Bs, kb);
            stageA(As, kb, 0, 0);
            stageB(Bs, kb, 0, 0);
            stageA(As, kb, 1, 0);
            stageB(Bs, kb, 1, 0);
            VMF(3);
            BAR();
        }
        for (int t = 0; t < ksteps; ++t) {
            const int d = t & 1;
            const bool h1 = (t + 1 < ksteps);
            const u16* aBuf = lsA + d * ABUF;
            const u16* bBuf = lsB + d * 16384;
            const u16 *As1, *Bs1; int kb1;
            resolve(h1 ? t + 1 : t, As1, Bs1, kb1);
            bf16x8 a[4], b[4];
            // p0: reads s0; stage (t+1).s0; FENCE: drain st(t).s1
            {
                const u16* ap = aBuf + wm * 2048 + l8;
#pragma unroll
                for (int i = 0; i < 4; ++i) a[i] = *(const bf16x8*)(ap + i * 512);
                const u16* bp = bBuf + wn * 2048 + l8;
#pragma unroll
                for (int j = 0; j < 4; ++j) b[j] = *(const bf16x8*)(bp + j * 512);
                if (h1) { stageA(As1, kb1, 0, d ^ 1); stageB(Bs1, kb1, 0, d ^ 1); VMF(3); }
                else { VMF(0); }
                BAR();
                __builtin_amdgcn_s_setprio(1);
#pragma unroll
                for (int i = 0; i < 4; ++i)
#pragma unroll
                    for (int j = 0; j < 4; ++j) acc[i][j] = MFMA16(a[i], b[j], acc[i][j]);
                __builtin_amdgcn_s_setprio(0);
                BAR();
            }
            // p1: reads s1; stage (t+1).s1; FENCE: drain st(t+1).s0
            {
                const u16* ap = aBuf + AS + wm * 2048 + l8;
#pragma unroll
                for (int i = 0; i < 4; ++i) a[i] = *(const bf16x8*)(ap + i * 512);
                const u16* bp = bBuf + 8192 + wn * 2048 + l8;
#pragma unroll
                for (int j = 0; j < 4; ++j) b[j] = *(const bf16x8*)(bp + j * 512);
                if (h1) { stageA(As1, kb1, 1, d ^ 1); stageB(Bs1, kb1, 1, d ^ 1); VMF(3); }
                BAR();
                __builtin_amdgcn_s_setprio(1);
#pragma unroll
                for (int i = 0; i < 4; ++i)
#pragma unroll
                    for (int j = 0; j < 4; ++j) acc[i][j] = MFMA16(a[i], b[j], acc[i][j]);
                __builtin_amdgcn_s_setprio(0);
                BAR();
            }
        }
    }

    // epilogue: C/D layout col=lane&15, row=(lane>>4)*4+reg (R1-verified)
    const int crow = m0 + wm * (BM / 2) + (lane >> 4) * 4;
    const int ccol = n0 + wn * 64 + rlane;
#pragma unroll
    for (int i = 0; i < MFR; ++i) {
#pragma unroll
        for (int j = 0; j < 4; ++j) {
            const int nn = ccol + j * 16;
            if (NGUARD && nn >= Nbuf) continue;
#pragma unroll
            for (int rr = 0; rr < 4; ++rr) {
                const int mm = crow + i * 16 + rr;
                const long off = (long)mm * ldc + nn;
                float v = acc[i][j][rr];
                if (NGUARD && nn >= Nlim) v = 0.f;
                if (SPLIT_OUT) {
                    u16 hh = f2bf(v);
                    Chi[off] = hh;
                    Clo[off] = f2bf(v - bf2f(hh));
                } else {
                    C[off] = v;
                }
            }
        }
    }
}

// ---------------- host ----------------

extern "C" void kernel_launch(void* const* d_in, const int* in_sizes, int n_in,
                              void* d_out, int out_size, void* d_ws, size_t ws_size,
                              hipStream_t stream) {
    const float* h = (const float*)d_in[0];
    const float* W = (const float*)d_in[1];
    float* out = (float*)d_out;

    char* ws = (char*)d_ws;
    size_t off = 0;
    auto alloc = [&](size_t bytes) -> void* {
        void* p = ws + off;
        off += (bytes + 255) & ~(size_t)255;
        return p;
    };
    const size_t MD = (size_t)M1 * KP;
    u16* h_hi  = (u16*)alloc(MD * 2);
    u16* h_lo  = (u16*)alloc(MD * 2);
    u16* hW_hi = (u16*)alloc(MD * 2);
    u16* hW_lo = (u16*)alloc(MD * 2);
    u16* hT    = (u16*)alloc((size_t)BB * 1024 * SS * 2);
    u16* Wt_hi = (u16*)alloc((size_t)1024 * KP * 2);
    u16* Wt_lo = (u16*)alloc((size_t)1024 * KP * 2);
    float* scores = (float*)alloc((size_t)4 * SS * SS * 4);   // 4-batch chunk

    hipFuncSetAttribute(reinterpret_cast<const void*>(&gemm8<256, 1, 1, 1>),
                        hipFuncAttributeMaxDynamicSharedMemorySize, 131072);
    hipFuncSetAttribute(reinterpret_cast<const void*>(&gemm8<256, 1, 0, 0>),
                        hipFuncAttributeMaxDynamicSharedMemorySize, 131072);
    hipFuncSetAttribute(reinterpret_cast<const void*>(&gemm8<128, 0, 0, 1>),
                        hipFuncAttributeMaxDynamicSharedMemorySize, 98304);

    // prep
    hsplit_kernel<<<dim3(16384 * 208 / 256), dim3(256), 0, stream>>>(h, h_hi, h_lo);
    wsplit_kernel<<<dim3(1024 * KP / 256), dim3(256), 0, stream>>>(W, Wt_hi, Wt_lo);
    transpose_kernel<<<dim3(SS / 32, 32, BB), dim3(32, 8), 0, stream>>>(h_hi, hT);

    // GEMM1: hW = h @ W  (M=16384, N=1024pad, K'=39 tiles) split-out, zero k-pad
    gemm8<256, 1, 1, 1><<<dim3(256), dim3(512), 131072, stream>>>(
        h_hi, h_lo, KP,
        Wt_hi, Wt_lo, 0L, KP,
        nullptr, hW_hi, hW_lo,
        KP, DD, KP, 39, 64);

    for (int b0 = 0; b0 < BB; b0 += 4) {
        const long aoff = (long)b0 * SS * KP;
        // GEMM2: scores = hW @ h^T  (chunk M=8192 m-merged, N=2048/batch, K'=39)
        gemm8<256, 1, 0, 0><<<dim3(256), dim3(512), 131072, stream>>>(
            hW_hi + aoff, hW_lo + aoff, KP,
            h_hi + aoff, h_lo + aoff, (long)SS * KP, KP,
            scores, nullptr, nullptr,
            SS, SS, SS, 39, 32);
        // softmax rows -> bf16 attn in place (pitch 4096 u16)
        softmax_kernel<<<dim3(4 * SS), dim3(256), 0, stream>>>(scores);
        // PV: out = attn @ h  (chunk M=8192, N=1024pad, K=2048, BM=128)
        gemm8<128, 0, 0, 1><<<dim3(256), dim3(512), 98304, stream>>>(
            (const u16*)scores, nullptr, SS * 2,
            hT + (long)b0 * 1024 * SS, nullptr, (long)1024 * SS, SS,
            out + (long)b0 * SS * DD, nullptr, nullptr,
            DD, DD, DD, 32, 64);
    }
}

// Round 8
// 402.762 us; speedup vs baseline: 1.1288x; 1.0864x over previous
//
#include <hip/hip_runtime.h>
#include <hip/hip_bf16.h>
#include <stdint.h>

// ProjectiveAttention: out = softmax(h @ W @ h^T) @ h
// B=8, S=2048, D=800, all fp32 in/out.
// R8: m201-exact phase decomposition. Phase = (ksub, M-quadrant): reads
// 8/4/8/4 per K-tile (B-frags live across the quadrant pair), 16 MFMA/phase.
// LDS cell = [16 rows][64 k] XOR-swizzled (k ^= (row&7)<<3 u16); staging
// reads 128B/row segments (8 rows/gload, source pre-XOR'd, dest linear).
// One VMF(0) fence per K-tile at p3, >=2 phases after last stage issue.

#define BB 8
#define SS 2048
#define DD 800
#define KP 832            // K padded to 13*64
#define M1 (BB*SS)        // 16384

typedef unsigned short u16;
typedef __attribute__((ext_vector_type(8))) short bf16x8;
typedef __attribute__((ext_vector_type(4))) float f32x4;

#define MFMA16(A, B, C) __builtin_amdgcn_mfma_f32_16x16x32_bf16(A, B, C, 0, 0, 0)
#define VMF(N) asm volatile("s_waitcnt vmcnt(" #N ")" ::: "memory")
#define BAR() __builtin_amdgcn_s_barrier()

__device__ __forceinline__ u16 f2bf(float x) {
    uint32_t u = __float_as_uint(x);
    uint32_t r = (u + 0x7fffu + ((u >> 16) & 1u)) >> 16;  // RTN-even
    return (u16)r;
}
__device__ __forceinline__ float bf2f(u16 h) {
    return __uint_as_float(((uint32_t)h) << 16);
}
__device__ __forceinline__ void gload16(const void* g, void* l) {
    __builtin_amdgcn_global_load_lds((__attribute__((address_space(1))) void*)g,
                                     (__attribute__((address_space(3))) void*)l,
                                     16, 0, 0);
}

// ---------------- prep kernels ----------------

// h (fp32 [16384][800]) -> h_hi/h_lo (bf16 [16384][832], k-pad zeroed)
__global__ __launch_bounds__(256) void hsplit_kernel(const float* __restrict__ x,
                                                     u16* __restrict__ hi,
                                                     u16* __restrict__ lo) {
    int idx = blockIdx.x * 256 + threadIdx.x;   // 16384*208 groups of 4 cols
    int rw = idx / 208, g = idx - rw * 208;
    ushort4 hv = {0, 0, 0, 0}, lv = {0, 0, 0, 0};
    if (g < 200) {
        float4 v = *(const float4*)(x + (long)rw * DD + g * 4);
        u16 h0 = f2bf(v.x), h1 = f2bf(v.y), h2 = f2bf(v.z), h3 = f2bf(v.w);
        hv = (ushort4){h0, h1, h2, h3};
        lv = (ushort4){f2bf(v.x - bf2f(h0)), f2bf(v.y - bf2f(h1)),
                       f2bf(v.z - bf2f(h2)), f2bf(v.w - bf2f(h3))};
    }
    *(ushort4*)(hi + (long)rw * KP + g * 4) = hv;
    *(ushort4*)(lo + (long)rw * KP + g * 4) = lv;
}

// W (fp32 [800][800]) -> Wt_hi/Wt_lo (bf16 [1024][832], transposed, pads zeroed)
__global__ __launch_bounds__(256) void wsplit_kernel(const float* __restrict__ W,
                                                     u16* __restrict__ hi,
                                                     u16* __restrict__ lo) {
    int idx = blockIdx.x * 256 + threadIdx.x;   // 1024*832
    int e = idx / KP, d = idx - e * KP;
    float v = (e < DD && d < DD) ? W[(long)d * DD + e] : 0.f;
    u16 h = f2bf(v);
    hi[idx] = h;
    lo[idx] = f2bf(v - bf2f(h));
}

// h_hi (bf16 [8][2048][832]) -> hT (bf16 [8][1024][2048], pad rows zeroed)
__global__ void transpose_kernel(const u16* __restrict__ h_hi, u16* __restrict__ hT) {
    __shared__ u16 tile[32][33];
    int b = blockIdx.z;
    int t0 = blockIdx.x * 32, d0 = blockIdx.y * 32;
    int lx = threadIdx.x, ly = threadIdx.y;
    for (int i = ly; i < 32; i += 8) {
        int d = d0 + lx;
        tile[i][lx] = (d < DD) ? h_hi[((long)b * SS + t0 + i) * KP + d] : (u16)0;
    }
    __syncthreads();
    for (int i = ly; i < 32; i += 8) {
        hT[((long)b * 1024 + d0 + i) * SS + t0 + lx] = tile[lx][i];
    }
}

// ---------------- softmax (one block per row, in-place fp32 -> bf16 attn) ------

__global__ __launch_bounds__(256) void softmax_kernel(float* __restrict__ scores) {
    const long row = blockIdx.x;
    float* p = scores + row * (long)SS;
    const int tid = threadIdx.x;
    const int lane = tid & 63, wid = tid >> 6;
    __shared__ float red[8];

    float v[8];
    float mx = -3.4e38f;
#pragma unroll
    for (int j = 0; j < 8; ++j) { v[j] = p[tid + 256 * j]; mx = fmaxf(mx, v[j]); }
#pragma unroll
    for (int o = 32; o; o >>= 1) mx = fmaxf(mx, __shfl_xor(mx, o, 64));
    if (lane == 0) red[wid] = mx;
    __syncthreads();
    mx = fmaxf(fmaxf(red[0], red[1]), fmaxf(red[2], red[3]));

    float sum = 0.f;
#pragma unroll
    for (int j = 0; j < 8; ++j) { v[j] = __expf(v[j] - mx); sum += v[j]; }
#pragma unroll
    for (int o = 32; o; o >>= 1) sum += __shfl_xor(sum, o, 64);
    if (lane == 0) red[4 + wid] = sum;
    __syncthreads();
    const float inv = 1.f / (red[4] + red[5] + red[6] + red[7]);

    u16* attn = (u16*)p;
#pragma unroll
    for (int j = 0; j < 8; ++j) attn[tid + 256 * j] = f2bf(v[j] * inv);
}

// ---------------- deep-pipelined GEMM: C[m][n] = sum_k A[m][k]*B[n][k] ----------
// BM x 256 tile, BK=64, 512 threads (8 waves, 2M x 4N). M batch-merged; when
// sB!=0, batch = m0>>11. SPLIT3: K'=3K via per-K-tile variant
// (Ahi,Bhi)/(Ahi,Blo)/(Alo,Bhi).
//
// LDS: per operand per dbuf, cells of [16 rows][64 k] u16, XOR-swizzled:
// element (r, k) lives at u16 index cell*1024 + r*64 + (k ^ ((r&7)<<3)).
// Stage: gload16 covers 8 rows x 128B; dest = cell*1024 + j*512 + lane*8
// (linear); source col pre-XOR'd: scol = ((lane&7)*8) ^ ((lane>>3)<<3).
// Read (cell, ksub s): lane l -> r=l&15, u16 = r*64 + (((l>>4)*8+s*32)^((l&7)<<3));
// lanes 0-7 spread over all 32 banks, l and l+8 2-way alias (free).
//
// K-tile = 4 phases (s, q): reads 8/4/8/4 (q1 reuses b regs), 16 MFMA each.
// Stages: p0 = A(t+1)h0+B(t+1)h0, p1 = A(t+1)h1+B(t+1)h1 (4 gloads/wave each).
// Fence: single VMF(0) at p3 (>=2 phases after last issue -> expected no wait).

template <int BM, int SPLIT3, int SPLIT_OUT, int NGUARD>
__global__ __launch_bounds__(512, 2) void gemm8(
    const u16* __restrict__ Ahi, const u16* __restrict__ Alo, int lda,
    const u16* __restrict__ Bhi, const u16* __restrict__ Blo, long sB, int ldb,
    float* __restrict__ C, u16* __restrict__ Chi, u16* __restrict__ Clo,
    int ldc, int Nlim, int Nbuf, int ksteps, int gmt) {
    constexpr int ABUF = BM * 64;          // u16 per A dbuf
    constexpr int MFR = (BM == 256) ? 8 : 4;
    extern __shared__ u16 smem[];
    u16* lsA = smem;                       // [2][ABUF]
    u16* lsB = smem + 2 * ABUF;            // [2][16384]

    const int tid = threadIdx.x;
    const int lane = tid & 63, wid = tid >> 6;
    const int wm = wid >> 2, wn = wid & 3;

    // bijective XCD remap (m204) on linearized grid, mt-fastest
    const int nwg = gridDim.x;
    const int orig = blockIdx.x;
    const int q = nwg >> 3, r = nwg & 7;
    const int xcd = orig & 7;
    const int wg = (xcd < r ? xcd * (q + 1) : r * (q + 1) + (xcd - r) * q) + (orig >> 3);
    const int m0 = (wg % gmt) * BM;
    const int n0 = (wg / gmt) * 256;

    const long boff = sB ? (long)(m0 >> 11) * sB : 0;
    const u16* Bh = Bhi + boff;
    const u16* Bl = SPLIT3 ? (Blo + boff) : nullptr;

    // staging source coords: 8 rows x 128B per gload, col pre-XOR'd
    const int srow8 = lane >> 3;                                 // 0..7
    const int scol = ((lane & 7) * 8) ^ ((srow8 & 7) << 3);      // u16
    // fragment read offsets within cell (u16), ksub 0/1
    const int rds0 = (lane & 15) * 64 + ((((lane >> 4) * 8)) ^ ((lane & 7) << 3));
    const int rds1 = (lane & 15) * 64 + ((((lane >> 4) * 8) + 32) ^ ((lane & 7) << 3));

    f32x4 acc[MFR][4];
#pragma unroll
    for (int i = 0; i < MFR; ++i)
#pragma unroll
        for (int j = 0; j < 4; ++j) acc[i][j] = (f32x4){0.f, 0.f, 0.f, 0.f};

    auto resolve = [&](int t, const u16*& As, const u16*& Bs, int& kb) {
        if (SPLIT3) {
            int kk = t / 3, v = t - kk * 3;
            As = (v == 2) ? Alo : Ahi;
            Bs = (v == 1) ? Bl : Bh;
            kb = kk * 64;
        } else {
            As = Ahi; Bs = Bh; kb = t * 64;
        }
    };

    // stage one 128-row half (8 cells) of A: cells 8*hh + wid, 2 gloads/wave
    auto stA = [&](const u16* As, int kb, int hh, int d) {
        const int c = (BM == 256) ? (8 * hh + wid) : wid;
        const u16* src = As + (long)(m0 + c * 16 + srow8) * lda + kb + scol;
        u16* dst = lsA + d * ABUF + c * 1024 + lane * 8;
        gload16(src, dst);
        gload16(src + (long)8 * lda, dst + 512);
    };
    auto stB = [&](const u16* Bs, int kb, int hh, int d) {
        const int c = 8 * hh + wid;
        const u16* src = Bs + (long)(n0 + c * 16 + srow8) * ldb + kb + scol;
        u16* dst = lsB + d * 16384 + c * 1024 + lane * 8;
        gload16(src, dst);
        gload16(src + (long)8 * ldb, dst + 512);
    };

    if constexpr (BM == 256) {
        // prologue: stage tile 0 fully; full drain; barrier
        {
            const u16 *As, *Bs; int kb;
            resolve(0, As, Bs, kb);
            stA(As, kb, 0, 0); stB(Bs, kb, 0, 0);
            stA(As, kb, 1, 0); stB(Bs, kb, 1, 0);
            VMF(0);
            BAR();
        }
        for (int t = 0; t < ksteps; ++t) {
            const int d = t & 1;
            const bool h1 = (t + 1 < ksteps);
            const u16* aBuf = lsA + d * ABUF;
            const u16* bBuf = lsB + d * 16384;
            const u16 *As1, *Bs1; int kb1;
            resolve(h1 ? t + 1 : t, As1, Bs1, kb1);
            bf16x8 a[4], b[4];
            // p0 (s0,q0): 8 reads; stage A(t+1)h0 + B(t+1)h0
            {
#pragma unroll
                for (int i = 0; i < 4; ++i) a[i] = *(const bf16x8*)(aBuf + (wm * 8 + i) * 1024 + rds0);
#pragma unroll
                for (int j = 0; j < 4; ++j) b[j] = *(const bf16x8*)(bBuf + (wn * 4 + j) * 1024 + rds0);
                if (h1) { stA(As1, kb1, 0, d ^ 1); stB(Bs1, kb1, 0, d ^ 1); }
                BAR();
                __builtin_amdgcn_s_setprio(1);
#pragma unroll
                for (int i = 0; i < 4; ++i)
#pragma unroll
                    for (int j = 0; j < 4; ++j) acc[i][j] = MFMA16(a[i], b[j], acc[i][j]);
                __builtin_amdgcn_s_setprio(0);
                BAR();
            }
            // p1 (s0,q1): 4 reads (b reused); stage A(t+1)h1 + B(t+1)h1
            {
#pragma unroll
                for (int i = 0; i < 4; ++i) a[i] = *(const bf16x8*)(aBuf + (wm * 8 + 4 + i) * 1024 + rds0);
                if (h1) { stA(As1, kb1, 1, d ^ 1); stB(Bs1, kb1, 1, d ^ 1); }
                BAR();
                __builtin_amdgcn_s_setprio(1);
#pragma unroll
                for (int i = 0; i < 4; ++i)
#pragma unroll
                    for (int j = 0; j < 4; ++j) acc[4 + i][j] = MFMA16(a[i], b[j], acc[4 + i][j]);
                __builtin_amdgcn_s_setprio(0);
                BAR();
            }
            // p2 (s1,q0): 8 reads
            {
#pragma unroll
                for (int i = 0; i < 4; ++i) a[i] = *(const bf16x8*)(aBuf + (wm * 8 + i) * 1024 + rds1);
#pragma unroll
                for (int j = 0; j < 4; ++j) b[j] = *(const bf16x8*)(bBuf + (wn * 4 + j) * 1024 + rds1);
                BAR();
                __builtin_amdgcn_s_setprio(1);
#pragma unroll
                for (int i = 0; i < 4; ++i)
#pragma unroll
                    for (int j = 0; j < 4; ++j) acc[i][j] = MFMA16(a[i], b[j], acc[i][j]);
                __builtin_amdgcn_s_setprio(0);
                BAR();
            }
            // p3 (s1,q1): 4 reads; FENCE VMF(0) (stages issued >=2 phases ago)
            {
#pragma unroll
                for (int i = 0; i < 4; ++i) a[i] = *(const bf16x8*)(aBuf + (wm * 8 + 4 + i) * 1024 + rds1);
                if (h1) { VMF(0); }
                BAR();
                __builtin_amdgcn_s_setprio(1);
#pragma unroll
                for (int i = 0; i < 4; ++i)
#pragma unroll
                    for (int j = 0; j < 4; ++j) acc[4 + i][j] = MFMA16(a[i], b[j], acc[4 + i][j]);
                __builtin_amdgcn_s_setprio(0);
                BAR();
            }
        }
    } else {
        // BM=128: 2 phases (s0, s1), 8 reads + 16 MFMA each.
        // Stages all at p0 (A + both B halves = 6 gloads/wave); fence at p1.
        {
            const u16 *As, *Bs; int kb;
            resolve(0, As, Bs, kb);
            stA(As, kb, 0, 0); stB(Bs, kb, 0, 0); stB(Bs, kb, 1, 0);
            VMF(0);
            BAR();
        }
        for (int t = 0; t < ksteps; ++t) {
            const int d = t & 1;
            const bool h1 = (t + 1 < ksteps);
            const u16* aBuf = lsA + d * ABUF;
            const u16* bBuf = lsB + d * 16384;
            const u16 *As1, *Bs1; int kb1;
            resolve(h1 ? t + 1 : t, As1, Bs1, kb1);
            bf16x8 a[4], b[4];
            // p0 (s0): 8 reads; stage whole tile t+1
            {
#pragma unroll
                for (int i = 0; i < 4; ++i) a[i] = *(const bf16x8*)(aBuf + (wm * 4 + i) * 1024 + rds0);
#pragma unroll
                for (int j = 0; j < 4; ++j) b[j] = *(const bf16x8*)(bBuf + (wn * 4 + j) * 1024 + rds0);
                if (h1) { stA(As1, kb1, 0, d ^ 1); stB(Bs1, kb1, 0, d ^ 1); stB(Bs1, kb1, 1, d ^ 1); }
                BAR();
                __builtin_amdgcn_s_setprio(1);
#pragma unroll
                for (int i = 0; i < 4; ++i)
#pragma unroll
                    for (int j = 0; j < 4; ++j) acc[i][j] = MFMA16(a[i], b[j], acc[i][j]);
                __builtin_amdgcn_s_setprio(0);
                BAR();
            }
            // p1 (s1): 8 reads; FENCE VMF(0)
            {
#pragma unroll
                for (int i = 0; i < 4; ++i) a[i] = *(const bf16x8*)(aBuf + (wm * 4 + i) * 1024 + rds1);
#pragma unroll
                for (int j = 0; j < 4; ++j) b[j] = *(const bf16x8*)(bBuf + (wn * 4 + j) * 1024 + rds1);
                if (h1) { VMF(0); }
                BAR();
                __builtin_amdgcn_s_setprio(1);
#pragma unroll
                for (int i = 0; i < 4; ++i)
#pragma unroll
                    for (int j = 0; j < 4; ++j) acc[i][j] = MFMA16(a[i], b[j], acc[i][j]);
                __builtin_amdgcn_s_setprio(0);
                BAR();
            }
        }
    }

    // epilogue: C/D layout col=lane&15, row=(lane>>4)*4+reg (R1-verified)
    const int rlane = lane & 15;
    const int crow = m0 + wm * (BM / 2) + (lane >> 4) * 4;
    const int ccol = n0 + wn * 64 + rlane;
#pragma unroll
    for (int i = 0; i < MFR; ++i) {
#pragma unroll
        for (int j = 0; j < 4; ++j) {
            const int nn = ccol + j * 16;
            if (NGUARD && nn >= Nbuf) continue;
#pragma unroll
            for (int rr = 0; rr < 4; ++rr) {
                const int mm = crow + i * 16 + rr;
                const long off = (long)mm * ldc + nn;
                float v = acc[i][j][rr];
                if (NGUARD && nn >= Nlim) v = 0.f;
                if (SPLIT_OUT) {
                    u16 hh = f2bf(v);
                    Chi[off] = hh;
                    Clo[off] = f2bf(v - bf2f(hh));
                } else {
                    C[off] = v;
                }
            }
        }
    }
}

// ---------------- host ----------------

extern "C" void kernel_launch(void* const* d_in, const int* in_sizes, int n_in,
                              void* d_out, int out_size, void* d_ws, size_t ws_size,
                              hipStream_t stream) {
    const float* h = (const float*)d_in[0];
    const float* W = (const float*)d_in[1];
    float* out = (float*)d_out;

    char* ws = (char*)d_ws;
    size_t off = 0;
    auto alloc = [&](size_t bytes) -> void* {
        void* p = ws + off;
        off += (bytes + 255) & ~(size_t)255;
        return p;
    };
    const size_t MD = (size_t)M1 * KP;
    u16* h_hi  = (u16*)alloc(MD * 2);
    u16* h_lo  = (u16*)alloc(MD * 2);
    u16* hW_hi = (u16*)alloc(MD * 2);
    u16* hW_lo = (u16*)alloc(MD * 2);
    u16* hT    = (u16*)alloc((size_t)BB * 1024 * SS * 2);
    u16* Wt_hi = (u16*)alloc((size_t)1024 * KP * 2);
    u16* Wt_lo = (u16*)alloc((size_t)1024 * KP * 2);
    float* scores = (float*)alloc((size_t)4 * SS * SS * 4);   // 4-batch chunk

    hipFuncSetAttribute(reinterpret_cast<const void*>(&gemm8<256, 1, 1, 1>),
                        hipFuncAttributeMaxDynamicSharedMemorySize, 131072);
    hipFuncSetAttribute(reinterpret_cast<const void*>(&gemm8<256, 1, 0, 0>),
                        hipFuncAttributeMaxDynamicSharedMemorySize, 131072);
    hipFuncSetAttribute(reinterpret_cast<const void*>(&gemm8<128, 0, 0, 1>),
                        hipFuncAttributeMaxDynamicSharedMemorySize, 98304);

    // prep
    hsplit_kernel<<<dim3(16384 * 208 / 256), dim3(256), 0, stream>>>(h, h_hi, h_lo);
    wsplit_kernel<<<dim3(1024 * KP / 256), dim3(256), 0, stream>>>(W, Wt_hi, Wt_lo);
    transpose_kernel<<<dim3(SS / 32, 32, BB), dim3(32, 8), 0, stream>>>(h_hi, hT);

    // GEMM1: hW = h @ W  (M=16384, N=1024pad, K'=39 tiles) split-out, zero k-pad
    gemm8<256, 1, 1, 1><<<dim3(256), dim3(512), 131072, stream>>>(
        h_hi, h_lo, KP,
        Wt_hi, Wt_lo, 0L, KP,
        nullptr, hW_hi, hW_lo,
        KP, DD, KP, 39, 64);

    for (int b0 = 0; b0 < BB; b0 += 4) {
        const long aoff = (long)b0 * SS * KP;
        // GEMM2: scores = hW @ h^T  (chunk M=8192 m-merged, N=2048/batch, K'=39)
        gemm8<256, 1, 0, 0><<<dim3(256), dim3(512), 131072, stream>>>(
            hW_hi + aoff, hW_lo + aoff, KP,
            h_hi + aoff, h_lo + aoff, (long)SS * KP, KP,
            scores, nullptr, nullptr,
            SS, SS, SS, 39, 32);
        // softmax rows -> bf16 attn in place (pitch 4096 u16)
        softmax_kernel<<<dim3(4 * SS), dim3(256), 0, stream>>>(scores);
        // PV: out = attn @ h  (chunk M=8192, N=1024pad, K=2048, BM=128)
        gemm8<128, 0, 0, 1><<<dim3(256), dim3(512), 98304, stream>>>(
            (const u16*)scores, nullptr, SS * 2,
            hT + (long)b0 * 1024 * SS, nullptr, (long)1024 * SS, SS,
            out + (long)b0 * SS * DD, nullptr, nullptr,
            DD, DD, DD, 32, 64);
    }
}